// Round 12
// baseline (129.987 us; speedup 1.0000x reference)
//
#include <hip/hip_runtime.h>

#define B_TOT 16384
#define NQ 7
#define H 64
#define MD 28

// ws layout (floats), dim-major [dim][B_TOT], lane-coalesced
#define OFF_A0 0               // [64][B] M-net L0 pre-act
#define OFF_A1 (64*B_TOT)      // [64][B] M-net L1 pre-act
#define OFF_X  (128*B_TOT)     // [28][B]
#define OFF_XD (156*B_TOT)     // [28][B]
#define OFF_SV (184*B_TOT)     // [28][B]
#define OFF_RP (212*B_TOT)     // [7][B]
#define OFF_MI (219*B_TOT)     // [28][B]
#define OFF_G  (247*B_TOT)     // [7][B]

#define OIDX(hi,lo) ((hi)*((hi)-1)/2 + (lo))

__device__ __forceinline__ float fast_rcp(float x){ return __builtin_amdgcn_rcpf(x); }
__device__ __forceinline__ float sigmoid_f(float a){ return fast_rcp(1.0f + __expf(-a)); }
__device__ __forceinline__ float softplus_f(float a){ return fmaxf(a,0.0f) + __logf(1.0f + __expf(-fabsf(a))); }

// ---- 8-lane-group swizzle helpers (compile-time immediates; groups don't cross 32-lane halves)
#define SWZF(v, imm) __int_as_float(__builtin_amdgcn_ds_swizzle(__float_as_int(v), (imm)))
#define BC(S) (((S)<<5)|0x18)      // broadcast sub-lane S within 8-group
#define XR(X) (((X)<<10)|0x1F)     // lane ^= X within 32

// one Jacobi rotation (P,Q) with columns distributed on 8 lanes/element
#define JROT(P,Q) { \
    float app = SWZF(Ac[P], BC(P)); \
    float aqq = SWZF(Ac[Q], BC(Q)); \
    float apq = SWZF(Ac[P], BC(Q)); \
    bool rot = fabsf(apq) > 1e-20f; \
    float apqs = rot ? apq : 1.0f; \
    float th = (aqq-app)*fast_rcp(2.0f*apqs); \
    float tt = fast_rcp(fabsf(th)+sqrtf(fmaf(th,th,1.0f))); \
    tt = (th<0.0f)? -tt : tt; \
    tt = rot ? tt : 0.0f; \
    float cc = rsqrtf(fmaf(tt,tt,1.0f)); \
    float ss = tt*cc; \
    bool isP = (j==(P)), isQ = (j==(Q)); \
    bool inPQ = isP || isQ; \
    float sgn = isP ? -ss : ss; \
    _Pragma("unroll") \
    for (int k=0;k<7;k++){ \
        float oa = SWZF(Ac[k], XR((P)^(Q))); \
        float na = fmaf(sgn, oa, cc*Ac[k]); \
        Ac[k] = inPQ ? na : Ac[k]; \
        float ov = SWZF(Vc[k], XR((P)^(Q))); \
        float nv = fmaf(sgn, ov, cc*Vc[k]); \
        Vc[k] = inPQ ? nv : Vc[k]; \
    } \
    float tP=Ac[P], tQ=Ac[Q]; \
    Ac[P] = fmaf(cc,tP,-ss*tQ); \
    Ac[Q] = fmaf(ss,tP, cc*tQ); \
    Ac[Q] = isP ? 0.0f : Ac[Q]; \
    Ac[P] = isQ ? 0.0f : Ac[P]; \
}

#define GV(k) { \
    Vg[(k)*7+0]=SWZF(Vc[k],BC(0)); Vg[(k)*7+1]=SWZF(Vc[k],BC(1)); \
    Vg[(k)*7+2]=SWZF(Vc[k],BC(2)); Vg[(k)*7+3]=SWZF(Vc[k],BC(3)); \
    Vg[(k)*7+4]=SWZF(Vc[k],BC(4)); Vg[(k)*7+5]=SWZF(Vc[k],BC(5)); \
    Vg[(k)*7+6]=SWZF(Vc[k],BC(6)); }

// ======== K1: M-net fwd + JVP (8 waves, k-outer) — unchanged from R11 ========
__global__ __launch_bounds__(512) void k_mnet(
    const float* __restrict__ q, const float* __restrict__ dq,
    const float* __restrict__ WM0, const float* __restrict__ bM0,
    const float* __restrict__ WM1, const float* __restrict__ bM1,
    const float* __restrict__ WM2, const float* __restrict__ bM2,
    float* __restrict__ ws)
{
    __shared__ __align__(16) float2 zj[H*64];
    __shared__ __align__(16) float  w1t[H*H];
    __shared__ __align__(16) float  w2t[H*MD];
    const int tid=threadIdx.x, lane=tid&63, wid=tid>>6;
    const int e = blockIdx.x*64 + lane;

    float qv[NQ], dqv[NQ];
    #pragma unroll
    for (int d=0;d<NQ;d++){ qv[d]=q[e*NQ+d]; dqv[d]=dq[e*NQ+d]; }

    for (int t=tid; t<H*H; t+=512)  w1t[(t&63)*H  + (t>>6)] = WM1[t];
    for (int t=tid; t<MD*H; t+=512) w2t[(t&63)*MD + (t>>6)] = WM2[t];

    #pragma unroll
    for (int oo=0;oo<8;oo++){
        const int o = wid*8+oo;
        float a=bM0[o], jd=0.f;
        #pragma unroll
        for (int d=0;d<NQ;d++){ float w=WM0[o*NQ+d]; a=fmaf(w,qv[d],a); jd=fmaf(w,dqv[d],jd); }
        ws[OFF_A0 + o*B_TOT + e] = a;
        zj[o*64+lane] = make_float2(softplus_f(a), sigmoid_f(a)*jd);
    }
    __syncthreads();

    float a1[8], jd1[8];
    #pragma unroll
    for (int oo=0;oo<8;oo++){ a1[oo]=bM1[wid*8+oo]; jd1[oo]=0.f; }
    #pragma unroll 4
    for (int k=0;k<H;k++){
        float2 z = zj[k*64+lane];
        float wv[8];
        *(float4*)&wv[0] = *(const float4*)&w1t[k*H + wid*8];
        *(float4*)&wv[4] = *(const float4*)&w1t[k*H + wid*8 + 4];
        #pragma unroll
        for (int oo=0;oo<8;oo++){ a1[oo]=fmaf(wv[oo],z.x,a1[oo]); jd1[oo]=fmaf(wv[oo],z.y,jd1[oo]); }
    }
    #pragma unroll
    for (int oo=0;oo<8;oo++) ws[OFF_A1 + (wid*8+oo)*B_TOT + e] = a1[oo];
    __syncthreads();
    #pragma unroll
    for (int oo=0;oo<8;oo++){
        float s1=sigmoid_f(a1[oo]);
        zj[(wid*8+oo)*64+lane] = make_float2(softplus_f(a1[oo]), s1*jd1[oo]);
    }
    __syncthreads();

    if (wid<7){
        float x[4], xd[4];
        #pragma unroll
        for (int mm=0;mm<4;mm++){ x[mm]=bM2[wid*4+mm]; xd[mm]=0.f; }
        #pragma unroll 4
        for (int k=0;k<H;k++){
            float2 z = zj[k*64+lane];
            float wv[4];
            *(float4*)&wv[0] = *(const float4*)&w2t[k*MD + wid*4];
            #pragma unroll
            for (int mm=0;mm<4;mm++){ x[mm]=fmaf(wv[mm],z.x,x[mm]); xd[mm]=fmaf(wv[mm],z.y,xd[mm]); }
        }
        #pragma unroll
        for (int mm=0;mm<4;mm++){
            ws[OFF_X +(wid*4+mm)*B_TOT+e]=x[mm];
            ws[OFF_XD+(wid*4+mm)*B_TOT+e]=xd[mm];
        }
    }
}

// ======== K2: V-net fwd + reverse -> g (8 waves) — unchanged from R11 ========
__global__ __launch_bounds__(512) void k_vnet(
    const float* __restrict__ q,
    const float* __restrict__ WV0, const float* __restrict__ bV0,
    const float* __restrict__ WV1, const float* __restrict__ bV1,
    const float* __restrict__ WV2,
    float* __restrict__ ws)
{
    __shared__ __align__(16) float zv0s[H*64];
    __shared__ __align__(16) float s0s [H*64];
    __shared__ __align__(16) float wv1t[H*H];
    const int tid=threadIdx.x, lane=tid&63, wid=tid>>6;
    const int e = blockIdx.x*64 + lane;

    float qv[NQ];
    #pragma unroll
    for (int d=0;d<NQ;d++) qv[d]=q[e*NQ+d];

    for (int t=tid; t<H*H; t+=512) wv1t[(t&63)*H + (t>>6)] = WV1[t];

    #pragma unroll
    for (int oo=0;oo<8;oo++){
        const int o=wid*8+oo;
        float a=bV0[o];
        #pragma unroll
        for (int d=0;d<NQ;d++) a=fmaf(WV0[o*NQ+d],qv[d],a);
        zv0s[o*64+lane]=softplus_f(a);
        s0s [o*64+lane]=sigmoid_f(a);
    }
    __syncthreads();

    float av1[8];
    #pragma unroll
    for (int oo=0;oo<8;oo++) av1[oo]=bV1[wid*8+oo];
    #pragma unroll 4
    for (int k=0;k<H;k++){
        float zk = zv0s[k*64+lane];
        float wv[8];
        *(float4*)&wv[0] = *(const float4*)&wv1t[k*H + wid*8];
        *(float4*)&wv[4] = *(const float4*)&wv1t[k*H + wid*8 + 4];
        #pragma unroll
        for (int oo=0;oo<8;oo++) av1[oo]=fmaf(wv[oo],zk,av1[oo]);
    }
    float r1o[8];
    #pragma unroll
    for (int oo=0;oo<8;oo++) r1o[oo] = WV2[wid*8+oo]*sigmoid_f(av1[oo]);

    float racc[64];
    #pragma unroll
    for (int k=0;k<H;k++) racc[k]=0.f;
    #pragma unroll
    for (int oo=0;oo<8;oo++){
        const int o=wid*8+oo;
        #pragma unroll
        for (int k=0;k<H;k++) racc[k]=fmaf(WV1[o*H+k],r1o[oo],racc[k]);
    }
    float gp[NQ];
    #pragma unroll
    for (int d=0;d<NQ;d++) gp[d]=0.f;
    #pragma unroll
    for (int k=0;k<H;k++){
        float r0f = s0s[k*64+lane]*racc[k];
        #pragma unroll
        for (int d=0;d<NQ;d++) gp[d]=fmaf(WV0[k*NQ+d],r0f,gp[d]);
    }
    __syncthreads();
    float* red = zv0s;
    #pragma unroll
    for (int d=0;d<NQ;d++) red[(wid*NQ+d)*64+lane]=gp[d];
    __syncthreads();
    if (wid==0){
        #pragma unroll
        for (int w2=1;w2<8;w2++){
            #pragma unroll
            for (int d=0;d<NQ;d++) gp[d]+=red[(w2*NQ+d)*64+lane];
        }
        #pragma unroll
        for (int d=0;d<NQ;d++) ws[OFF_G + d*B_TOT + e]=gp[d];
    }
}

// ======== K3: eigen, 8 lanes/element parallel Jacobi + redundant contractions ========
__global__ __launch_bounds__(512) void kb_eigen(
    const float* __restrict__ dq, const float* __restrict__ tau,
    float* __restrict__ ws)
{
    __shared__ float xs [MD*64];
    __shared__ float xds[MD*64];
    __shared__ float dqs[NQ*64];
    __shared__ float taus[NQ*64];
    const int tid = threadIdx.x;
    const int base = blockIdx.x*64;

    // coalesced stage-in
    for (int t=tid; t<MD*64; t+=512){
        int m=t>>6, el=t&63;
        xs [t]=ws[OFF_X +m*B_TOT+base+el];
        xds[t]=ws[OFF_XD+m*B_TOT+base+el];
    }
    for (int t=tid; t<NQ*64; t+=512){
        int d=t>>6, el=t&63;
        dqs [t]=dq [(base+el)*NQ+d];
        taus[t]=tau[(base+el)*NQ+d];
    }
    __syncthreads();

    const int g = tid>>3;        // element sub-index 0..63
    const int j = tid&7;         // column owner 0..6 (7 = spare, stores masked)
    const int e = base + g;
    const int jtri = j*(j-1)/2;

    // load column j of U (symmetric) + identity V column
    float Ac[7], Vc[7];
    #pragma unroll
    for (int k=0;k<7;k++){
        int idx = (k==j) ? k
                : (k>j ? (NQ + k*(k-1)/2 + j) : (NQ + jtri + k));
        Ac[k] = xs[idx*64+g];
        Vc[k] = (k==j)? 1.0f : 0.0f;
    }

    // 5 cyclic sweeps, rotations executed wave-wide (8 elements per wave)
    #pragma unroll 1
    for (int sweep=0; sweep<5; sweep++){
        JROT(0,1) JROT(0,2) JROT(0,3) JROT(0,4) JROT(0,5) JROT(0,6)
        JROT(1,2) JROT(1,3) JROT(1,4) JROT(1,5) JROT(1,6)
        JROT(2,3) JROT(2,4) JROT(2,5) JROT(2,6)
        JROT(3,4) JROT(3,5) JROT(3,6)
        JROT(4,5) JROT(4,6)
        JROT(5,6)
    }

    // extract own eigenvalue (no runtime reg-indexing), broadcast all
    float lam = Ac[0];
    #pragma unroll
    for (int k=1;k<7;k++) lam = (j==k)? Ac[k] : lam;
    float Ad[7];
    Ad[0]=SWZF(lam,BC(0)); Ad[1]=SWZF(lam,BC(1)); Ad[2]=SWZF(lam,BC(2));
    Ad[3]=SWZF(lam,BC(3)); Ad[4]=SWZF(lam,BC(4)); Ad[5]=SWZF(lam,BC(5));
    Ad[6]=SWZF(lam,BC(6));

    // gather full V (row-major Vg[k][b] = V[k][b]) on every lane
    float Vg[49];
    GV(0) GV(1) GV(2) GV(3) GV(4) GV(5) GV(6)

    float ee[7];
    #pragma unroll
    for (int i=0;i<7;i++) ee[i]=__expf(Ad[i]);

    float Ro[21];
    #pragma unroll
    for (int p=0;p<6;p++){
        #pragma unroll
        for (int qj=p+1;qj<7;qj++){
            float d = Ad[p]-Ad[qj];
            bool big = fabsf(d) > 1e-3f;
            float den = big ? d : 1.0f;
            float exact = (ee[p]-ee[qj])*fast_rcp(den);
            float ser = sqrtf(ee[p]*ee[qj]) * fmaf(d*d,(1.0f/24.0f),1.0f);
            Ro[OIDX(qj,p)] = big ? exact : ser;
        }
    }

    float dqv[7];
    #pragma unroll
    for (int d=0;d<7;d++) dqv[d]=dqs[d*64+g];

    float w[7];
    #pragma unroll
    for (int a=0;a<7;a++){
        float acc=0.0f;
        #pragma unroll
        for (int k=0;k<7;k++) acc=fmaf(Vg[k*7+a],dqv[k],acc);
        w[a]=acc;
    }

    {   // sv cotangent: S = V (R o wwT) V^T, offdiag doubled; masked stores
        float Yd[7], Yo[21];
        #pragma unroll
        for (int a=0;a<7;a++) Yd[a]=ee[a]*w[a]*w[a];
        #pragma unroll
        for (int p=0;p<6;p++){
            #pragma unroll
            for (int qj=p+1;qj<7;qj++) Yo[OIDX(qj,p)]=Ro[OIDX(qj,p)]*w[p]*w[qj];
        }
        float P[49];
        #pragma unroll
        for (int i=0;i<7;i++){
            #pragma unroll
            for (int a=0;a<7;a++){
                float acc=0.0f;
                #pragma unroll
                for (int c=0;c<7;c++){
                    float y=(c==a)? Yd[a] : ((c<a)? Yo[OIDX(a,c)] : Yo[OIDX(c,a)]);
                    acc=fmaf(Vg[i*7+c],y,acc);
                }
                P[i*7+a]=acc;
            }
        }
        #pragma unroll
        for (int i=0;i<7;i++){
            #pragma unroll
            for (int jj=i;jj<7;jj++){
                float acc=0.0f;
                #pragma unroll
                for (int a=0;a<7;a++) acc=fmaf(P[i*7+a],Vg[jj*7+a],acc);
                int m = (i==jj)? i : (NQ+OIDX(jj,i));
                float val = (i==jj)? acc : 2.0f*acc;
                if ((m%7)==j) ws[OFF_SV + m*B_TOT + e]=val;
            }
        }
    }

    {   // rp = tau - V (R o (V^T Udot V)) V^T dq ; masked stores
        float xd[MD];
        #pragma unroll
        for (int m=0;m<MD;m++) xd[m]=xds[m*64+g];
        float P2[49];
        #pragma unroll
        for (int i=0;i<7;i++){
            #pragma unroll
            for (int a=0;a<7;a++){
                float acc=0.0f;
                #pragma unroll
                for (int k=0;k<7;k++){
                    float u=(i==k)? xd[i] : ((k<i)? xd[NQ+OIDX(i,k)] : xd[NQ+OIDX(k,i)]);
                    acc=fmaf(u,Vg[k*7+a],acc);
                }
                P2[i*7+a]=acc;
            }
        }
        float Td[7], To[21];
        #pragma unroll
        for (int a=0;a<7;a++){
            float acc=0.0f;
            #pragma unroll
            for (int i=0;i<7;i++) acc=fmaf(Vg[i*7+a],P2[i*7+a],acc);
            Td[a]=acc;
        }
        #pragma unroll
        for (int a=0;a<6;a++){
            #pragma unroll
            for (int bb=a+1;bb<7;bb++){
                float acc=0.0f;
                #pragma unroll
                for (int i=0;i<7;i++) acc=fmaf(Vg[i*7+a],P2[i*7+bb],acc);
                To[OIDX(bb,a)]=acc;
            }
        }
        float zw[7];
        #pragma unroll
        for (int a=0;a<7;a++){
            float acc=ee[a]*Td[a]*w[a];
            #pragma unroll
            for (int bb=0;bb<7;bb++){
                if (bb==a) continue;
                float z=(bb<a)? (Ro[OIDX(a,bb)]*To[OIDX(a,bb)]) : (Ro[OIDX(bb,a)]*To[OIDX(bb,a)]);
                acc=fmaf(z,w[bb],acc);
            }
            zw[a]=acc;
        }
        #pragma unroll
        for (int i=0;i<7;i++){
            float acc=0.0f;
            #pragma unroll
            for (int a=0;a<7;a++) acc=fmaf(Vg[i*7+a],zw[a],acc);
            if (i==j) ws[OFF_RP + i*B_TOT + e] = taus[i*64+g]-acc;
        }
    }

    // Minv = V diag(1/ee) V^T ; masked stores
    {
        float iee[7];
        #pragma unroll
        for (int a=0;a<7;a++) iee[a]=fast_rcp(ee[a]);
        #pragma unroll
        for (int i=0;i<7;i++){
            #pragma unroll
            for (int jj=i;jj<7;jj++){
                float acc=0.0f;
                #pragma unroll
                for (int a=0;a<7;a++) acc=fmaf(Vg[i*7+a]*iee[a],Vg[jj*7+a],acc);
                int m = (i==jj)? i : (NQ+OIDX(jj,i));
                if ((m%7)==j) ws[OFF_MI + m*B_TOT + e]=acc;
            }
        }
    }
}

// ======== K4: M-net reverse (s), rhs, SPD solve -> out; 8 waves — unchanged ========
__global__ __launch_bounds__(512) void kd_solve(
    const float* __restrict__ WM0, const float* __restrict__ WM1, const float* __restrict__ WM2,
    const float* __restrict__ ws,
    float* __restrict__ out)
{
    __shared__ __align__(16) float w2t[H*MD];
    __shared__ float rr1fs[H*64];
    __shared__ float s0s[H*64];
    const int tid=threadIdx.x, lane=tid&63, wid=tid>>6;
    const int e = blockIdx.x*64+lane;

    for (int t=tid;t<MD*H;t+=512) w2t[(t&63)*MD+(t>>6)] = WM2[t];

    float sv[MD];
    #pragma unroll
    for (int m=0;m<MD;m++) sv[m]=ws[OFF_SV+m*B_TOT+e];
    __syncthreads();

    #pragma unroll
    for (int kk=0;kk<8;kk++){
        const int k=wid*8+kk;
        float wv[MD];
        #pragma unroll
        for (int c=0;c<7;c++) *(float4*)&wv[c*4] = *(const float4*)&w2t[k*MD + c*4];
        float acc=0.f;
        #pragma unroll
        for (int m=0;m<MD;m++) acc=fmaf(wv[m],sv[m],acc);
        float a1k=ws[OFF_A1+k*B_TOT+e];
        rr1fs[k*64+lane]=sigmoid_f(a1k)*acc;
        float a0k=ws[OFF_A0+k*B_TOT+e];
        s0s[k*64+lane]=sigmoid_f(a0k);
    }
    __syncthreads();

    float u[64];
    #pragma unroll
    for (int k=0;k<H;k++) u[k]=0.f;
    #pragma unroll
    for (int ii=0;ii<8;ii++){
        const int i=wid*8+ii;
        float r=rr1fs[i*64+lane];
        #pragma unroll
        for (int k=0;k<H;k++) u[k]=fmaf(WM1[i*H+k],r,u[k]);
    }

    float sp[NQ];
    #pragma unroll
    for (int d=0;d<NQ;d++) sp[d]=0.f;
    #pragma unroll
    for (int k=0;k<H;k++){
        float t2=s0s[k*64+lane]*u[k];
        #pragma unroll
        for (int d=0;d<NQ;d++) sp[d]=fmaf(WM0[k*NQ+d],t2,sp[d]);
    }
    __syncthreads();
    float* red = rr1fs;
    #pragma unroll
    for (int d=0;d<NQ;d++) red[(wid*NQ+d)*64+lane]=sp[d];
    __syncthreads();

    if (wid==0){
        #pragma unroll
        for (int w2=1;w2<8;w2++){
            #pragma unroll
            for (int d=0;d<NQ;d++) sp[d]+=red[(w2*NQ+d)*64+lane];
        }
        float rhs[NQ], mi[MD];
        #pragma unroll
        for (int d=0;d<NQ;d++)
            rhs[d] = ws[OFF_RP + d*B_TOT + e] + 0.5f*sp[d] - ws[OFF_G + d*B_TOT + e];
        #pragma unroll
        for (int t=0;t<MD;t++) mi[t]=ws[OFF_MI + t*B_TOT + e];
        #pragma unroll
        for (int i=0;i<NQ;i++){
            float acc=0.0f;
            #pragma unroll
            for (int jj=0;jj<NQ;jj++){
                int idx=(jj==i)? i : (NQ + ((jj>i)? OIDX(jj,i) : OIDX(i,jj)));
                acc=fmaf(mi[idx],rhs[jj],acc);
            }
            out[e*NQ+i]=acc;
        }
    }
}

extern "C" void kernel_launch(void* const* d_in, const int* in_sizes, int n_in,
                              void* d_out, int out_size, void* d_ws, size_t ws_size,
                              hipStream_t stream) {
    const float* q   = (const float*)d_in[0];
    const float* dq  = (const float*)d_in[1];
    const float* tau = (const float*)d_in[2];
    const float* WM0 = (const float*)d_in[3];
    const float* bM0 = (const float*)d_in[4];
    const float* WM1 = (const float*)d_in[5];
    const float* bM1 = (const float*)d_in[6];
    const float* WM2 = (const float*)d_in[7];
    const float* bM2 = (const float*)d_in[8];
    const float* WV0 = (const float*)d_in[9];
    const float* bV0 = (const float*)d_in[10];
    const float* WV1 = (const float*)d_in[11];
    const float* bV1 = (const float*)d_in[12];
    const float* WV2 = (const float*)d_in[13];
    float* ws  = (float*)d_ws;
    float* out = (float*)d_out;

    hipLaunchKernelGGL(k_mnet,   dim3(B_TOT/64), dim3(512), 0, stream,
                       q, dq, WM0, bM0, WM1, bM1, WM2, bM2, ws);
    hipLaunchKernelGGL(k_vnet,   dim3(B_TOT/64), dim3(512), 0, stream,
                       q, WV0, bV0, WV1, bV1, WV2, ws);
    hipLaunchKernelGGL(kb_eigen, dim3(B_TOT/64), dim3(512), 0, stream, dq, tau, ws);
    hipLaunchKernelGGL(kd_solve, dim3(B_TOT/64), dim3(512), 0, stream,
                       WM0, WM1, WM2, ws, out);
}

// Round 13
// 69.016 us; speedup vs baseline: 1.8834x; 1.8834x over previous
//
#include <hip/hip_runtime.h>

#define B_TOT 16384
#define NQ 7
#define H 64
#define MD 28

// ws layout (floats), dim-major [dim][B_TOT], lane-coalesced
#define OFF_A0 0               // [64][B] M-net L0 pre-act
#define OFF_A1 (64*B_TOT)      // [64][B] M-net L1 pre-act
#define OFF_X  (128*B_TOT)     // [28][B]
#define OFF_XD (156*B_TOT)     // [28][B]
#define OFF_SV (184*B_TOT)     // [28][B]
#define OFF_RP (212*B_TOT)     // [7][B]
#define OFF_MI (219*B_TOT)     // [28][B]
#define OFF_G  (247*B_TOT)     // [7][B]

#define OIDX(hi,lo) ((hi)*((hi)-1)/2 + (lo))

__device__ __forceinline__ float fast_rcp(float x){ return __builtin_amdgcn_rcpf(x); }
__device__ __forceinline__ float sigmoid_f(float a){ return fast_rcp(1.0f + __expf(-a)); }
__device__ __forceinline__ float softplus_f(float a){ return fmaxf(a,0.0f) + __logf(1.0f + __expf(-fabsf(a))); }

// ---- parallel-order Jacobi helpers (verified R10/R11) ----
#define JANGLE(i,P,Q) \
    float apq##i = Ao[OIDX(Q,P)]; \
    bool  rot##i = fabsf(apq##i) > 1e-20f; \
    float apqs##i = rot##i ? apq##i : 1.0f; \
    float th##i = (Ad[Q]-Ad[P]) * fast_rcp(2.0f*apqs##i); \
    float tt##i = fast_rcp(fabsf(th##i)+sqrtf(fmaf(th##i,th##i,1.0f))); \
    tt##i = (th##i<0.0f)? -tt##i : tt##i; \
    tt##i = rot##i ? tt##i : 0.0f; \
    float cc##i = rsqrtf(fmaf(tt##i,tt##i,1.0f)); \
    float ss##i = tt##i*cc##i;

#define JAPPLY(i,P,Q) \
    { \
        _Pragma("unroll") \
        for (int j=0;j<7;j++){ \
            if (j==P || j==Q) continue; \
            float ajp = (j<P)? Ao[OIDX(P,j)] : Ao[OIDX(j,P)]; \
            float ajq = (j<Q)? Ao[OIDX(Q,j)] : Ao[OIDX(j,Q)]; \
            float np_ = fmaf(cc##i,ajp,-ss##i*ajq); \
            float nq_ = fmaf(ss##i,ajp, cc##i*ajq); \
            if (j<P) Ao[OIDX(P,j)] = np_; else Ao[OIDX(j,P)] = np_; \
            if (j<Q) Ao[OIDX(Q,j)] = nq_; else Ao[OIDX(j,Q)] = nq_; \
        } \
        Ad[P] = fmaf(-tt##i,apq##i,Ad[P]); \
        Ad[Q] = fmaf( tt##i,apq##i,Ad[Q]); \
        Ao[OIDX(Q,P)] = 0.0f; \
        _Pragma("unroll") \
        for (int j=0;j<7;j++){ \
            float vp=V[j*7+P], vq=V[j*7+Q]; \
            V[j*7+P] = fmaf(cc##i,vp,-ss##i*vq); \
            V[j*7+Q] = fmaf(ss##i,vp, cc##i*vq); \
        } \
    }

#define JROUND(P0,Q0,P1,Q1,P2,Q2) \
    { JANGLE(0,P0,Q0) JANGLE(1,P1,Q1) JANGLE(2,P2,Q2) \
      JAPPLY(0,P0,Q0) JAPPLY(1,P1,Q1) JAPPLY(2,P2,Q2) }

// ======== K1: M-net fwd + JVP (8 waves, k-outer) — unchanged from R11 ========
__global__ __launch_bounds__(512) void k_mnet(
    const float* __restrict__ q, const float* __restrict__ dq,
    const float* __restrict__ WM0, const float* __restrict__ bM0,
    const float* __restrict__ WM1, const float* __restrict__ bM1,
    const float* __restrict__ WM2, const float* __restrict__ bM2,
    float* __restrict__ ws)
{
    __shared__ __align__(16) float2 zj[H*64];
    __shared__ __align__(16) float  w1t[H*H];
    __shared__ __align__(16) float  w2t[H*MD];
    const int tid=threadIdx.x, lane=tid&63, wid=tid>>6;
    const int e = blockIdx.x*64 + lane;

    float qv[NQ], dqv[NQ];
    #pragma unroll
    for (int d=0;d<NQ;d++){ qv[d]=q[e*NQ+d]; dqv[d]=dq[e*NQ+d]; }

    for (int t=tid; t<H*H; t+=512)  w1t[(t&63)*H  + (t>>6)] = WM1[t];
    for (int t=tid; t<MD*H; t+=512) w2t[(t&63)*MD + (t>>6)] = WM2[t];

    #pragma unroll
    for (int oo=0;oo<8;oo++){
        const int o = wid*8+oo;
        float a=bM0[o], jd=0.f;
        #pragma unroll
        for (int d=0;d<NQ;d++){ float w=WM0[o*NQ+d]; a=fmaf(w,qv[d],a); jd=fmaf(w,dqv[d],jd); }
        ws[OFF_A0 + o*B_TOT + e] = a;
        zj[o*64+lane] = make_float2(softplus_f(a), sigmoid_f(a)*jd);
    }
    __syncthreads();

    float a1[8], jd1[8];
    #pragma unroll
    for (int oo=0;oo<8;oo++){ a1[oo]=bM1[wid*8+oo]; jd1[oo]=0.f; }
    #pragma unroll 4
    for (int k=0;k<H;k++){
        float2 z = zj[k*64+lane];
        float wv[8];
        *(float4*)&wv[0] = *(const float4*)&w1t[k*H + wid*8];
        *(float4*)&wv[4] = *(const float4*)&w1t[k*H + wid*8 + 4];
        #pragma unroll
        for (int oo=0;oo<8;oo++){ a1[oo]=fmaf(wv[oo],z.x,a1[oo]); jd1[oo]=fmaf(wv[oo],z.y,jd1[oo]); }
    }
    #pragma unroll
    for (int oo=0;oo<8;oo++) ws[OFF_A1 + (wid*8+oo)*B_TOT + e] = a1[oo];
    __syncthreads();
    #pragma unroll
    for (int oo=0;oo<8;oo++){
        float s1=sigmoid_f(a1[oo]);
        zj[(wid*8+oo)*64+lane] = make_float2(softplus_f(a1[oo]), s1*jd1[oo]);
    }
    __syncthreads();

    if (wid<7){
        float x[4], xd[4];
        #pragma unroll
        for (int mm=0;mm<4;mm++){ x[mm]=bM2[wid*4+mm]; xd[mm]=0.f; }
        #pragma unroll 4
        for (int k=0;k<H;k++){
            float2 z = zj[k*64+lane];
            float wv[4];
            *(float4*)&wv[0] = *(const float4*)&w2t[k*MD + wid*4];
            #pragma unroll
            for (int mm=0;mm<4;mm++){ x[mm]=fmaf(wv[mm],z.x,x[mm]); xd[mm]=fmaf(wv[mm],z.y,xd[mm]); }
        }
        #pragma unroll
        for (int mm=0;mm<4;mm++){
            ws[OFF_X +(wid*4+mm)*B_TOT+e]=x[mm];
            ws[OFF_XD+(wid*4+mm)*B_TOT+e]=xd[mm];
        }
    }
}

// ======== K2: V-net fwd + reverse -> g (8 waves) — unchanged from R11 ========
__global__ __launch_bounds__(512) void k_vnet(
    const float* __restrict__ q,
    const float* __restrict__ WV0, const float* __restrict__ bV0,
    const float* __restrict__ WV1, const float* __restrict__ bV1,
    const float* __restrict__ WV2,
    float* __restrict__ ws)
{
    __shared__ __align__(16) float zv0s[H*64];
    __shared__ __align__(16) float s0s [H*64];
    __shared__ __align__(16) float wv1t[H*H];
    const int tid=threadIdx.x, lane=tid&63, wid=tid>>6;
    const int e = blockIdx.x*64 + lane;

    float qv[NQ];
    #pragma unroll
    for (int d=0;d<NQ;d++) qv[d]=q[e*NQ+d];

    for (int t=tid; t<H*H; t+=512) wv1t[(t&63)*H + (t>>6)] = WV1[t];

    #pragma unroll
    for (int oo=0;oo<8;oo++){
        const int o=wid*8+oo;
        float a=bV0[o];
        #pragma unroll
        for (int d=0;d<NQ;d++) a=fmaf(WV0[o*NQ+d],qv[d],a);
        zv0s[o*64+lane]=softplus_f(a);
        s0s [o*64+lane]=sigmoid_f(a);
    }
    __syncthreads();

    float av1[8];
    #pragma unroll
    for (int oo=0;oo<8;oo++) av1[oo]=bV1[wid*8+oo];
    #pragma unroll 4
    for (int k=0;k<H;k++){
        float zk = zv0s[k*64+lane];
        float wv[8];
        *(float4*)&wv[0] = *(const float4*)&wv1t[k*H + wid*8];
        *(float4*)&wv[4] = *(const float4*)&wv1t[k*H + wid*8 + 4];
        #pragma unroll
        for (int oo=0;oo<8;oo++) av1[oo]=fmaf(wv[oo],zk,av1[oo]);
    }
    float r1o[8];
    #pragma unroll
    for (int oo=0;oo<8;oo++) r1o[oo] = WV2[wid*8+oo]*sigmoid_f(av1[oo]);

    float racc[64];
    #pragma unroll
    for (int k=0;k<H;k++) racc[k]=0.f;
    #pragma unroll
    for (int oo=0;oo<8;oo++){
        const int o=wid*8+oo;
        #pragma unroll
        for (int k=0;k<H;k++) racc[k]=fmaf(WV1[o*H+k],r1o[oo],racc[k]);
    }
    float gp[NQ];
    #pragma unroll
    for (int d=0;d<NQ;d++) gp[d]=0.f;
    #pragma unroll
    for (int k=0;k<H;k++){
        float r0f = s0s[k*64+lane]*racc[k];
        #pragma unroll
        for (int d=0;d<NQ;d++) gp[d]=fmaf(WV0[k*NQ+d],r0f,gp[d]);
    }
    __syncthreads();
    float* red = zv0s;
    #pragma unroll
    for (int d=0;d<NQ;d++) red[(wid*NQ+d)*64+lane]=gp[d];
    __syncthreads();
    if (wid==0){
        #pragma unroll
        for (int w2=1;w2<8;w2++){
            #pragma unroll
            for (int d=0;d<NQ;d++) gp[d]+=red[(w2*NQ+d)*64+lane];
        }
        #pragma unroll
        for (int d=0;d<NQ;d++) ws[OFF_G + d*B_TOT + e]=gp[d];
    }
}

// ======== K3: eigen serial per-lane, (64,1) no-spill, 4 sweeps ========
__global__ __launch_bounds__(64,1) void kb_eigen(
    const float* __restrict__ dq, const float* __restrict__ tau,
    float* __restrict__ ws)
{
    const int e = blockIdx.x*64 + threadIdx.x;

    float x[MD], xd[MD];
    #pragma unroll
    for (int m=0;m<MD;m++){ x[m]=ws[OFF_X+m*B_TOT+e]; xd[m]=ws[OFF_XD+m*B_TOT+e]; }

    float Ad[NQ], Ao[21], V[49];
    #pragma unroll
    for (int i=0;i<NQ;i++) Ad[i]=x[i];
    #pragma unroll
    for (int t=0;t<21;t++) Ao[t]=x[NQ+t];
    #pragma unroll
    for (int t=0;t<49;t++) V[t]=0.0f;
    #pragma unroll
    for (int i=0;i<NQ;i++) V[i*7+i]=1.0f;

    // 4 sweeps x 7 rounds x 3 disjoint pairs (ILP x3 on the angle chains)
    #pragma unroll 1
    for (int sweep=0; sweep<4; sweep++){
        JROUND(1,6, 2,5, 3,4)
        JROUND(0,2, 3,6, 4,5)
        JROUND(1,3, 0,4, 5,6)
        JROUND(2,4, 1,5, 0,6)
        JROUND(3,5, 2,6, 0,1)
        JROUND(4,6, 0,3, 1,2)
        JROUND(0,5, 1,4, 2,3)
    }

    float ee[7], iee[7];
    #pragma unroll
    for (int i=0;i<7;i++){ ee[i]=__expf(Ad[i]); iee[i]=fast_rcp(ee[i]); }

    float Ro[21];
    #pragma unroll
    for (int p=0;p<6;p++){
        #pragma unroll
        for (int qj=p+1;qj<7;qj++){
            float d = Ad[p]-Ad[qj];
            bool big = fabsf(d) > 1e-3f;
            float den = big ? d : 1.0f;
            float exact = (ee[p]-ee[qj])*fast_rcp(den);
            float ser = sqrtf(ee[p]*ee[qj]) * fmaf(d*d,(1.0f/24.0f),1.0f);
            Ro[OIDX(qj,p)] = big ? exact : ser;
        }
    }

    float dqv[7], tv[7];
    #pragma unroll
    for (int d=0;d<7;d++){ dqv[d]=dq[e*NQ+d]; tv[d]=tau[e*NQ+d]; }

    float w[7];
    #pragma unroll
    for (int a=0;a<7;a++){
        float acc=0.0f;
        #pragma unroll
        for (int j=0;j<7;j++) acc=fmaf(V[j*7+a],dqv[j],acc);
        w[a]=acc;
    }

    {   // sv cotangent: S = V (R o wwT) V^T, offdiag doubled
        float Yd[7], Yo[21];
        #pragma unroll
        for (int a=0;a<7;a++) Yd[a]=ee[a]*w[a]*w[a];
        #pragma unroll
        for (int p=0;p<6;p++){
            #pragma unroll
            for (int qj=p+1;qj<7;qj++) Yo[OIDX(qj,p)]=Ro[OIDX(qj,p)]*w[p]*w[qj];
        }
        float P[49];
        #pragma unroll
        for (int i=0;i<7;i++){
            #pragma unroll
            for (int a=0;a<7;a++){
                float acc=0.0f;
                #pragma unroll
                for (int c=0;c<7;c++){
                    float y=(c==a)? Yd[a] : ((c<a)? Yo[OIDX(a,c)] : Yo[OIDX(c,a)]);
                    acc=fmaf(V[i*7+c],y,acc);
                }
                P[i*7+a]=acc;
            }
        }
        #pragma unroll
        for (int i=0;i<7;i++){
            #pragma unroll
            for (int j=i;j<7;j++){
                float acc=0.0f;
                #pragma unroll
                for (int a=0;a<7;a++) acc=fmaf(P[i*7+a],V[j*7+a],acc);
                if (i==j) ws[OFF_SV + i*B_TOT + e]=acc;
                else      ws[OFF_SV + (NQ+OIDX(j,i))*B_TOT + e]=2.0f*acc;
            }
        }
    }

    {   // rp = tau - Mdot*dq
        float P2[49];
        #pragma unroll
        for (int i=0;i<7;i++){
            #pragma unroll
            for (int a=0;a<7;a++){
                float acc=0.0f;
                #pragma unroll
                for (int j=0;j<7;j++){
                    float u=(i==j)? xd[i] : ((j<i)? xd[NQ+OIDX(i,j)] : xd[NQ+OIDX(j,i)]);
                    acc=fmaf(u,V[j*7+a],acc);
                }
                P2[i*7+a]=acc;
            }
        }
        float Td[7], To[21];
        #pragma unroll
        for (int a=0;a<7;a++){
            float acc=0.0f;
            #pragma unroll
            for (int i=0;i<7;i++) acc=fmaf(V[i*7+a],P2[i*7+a],acc);
            Td[a]=acc;
        }
        #pragma unroll
        for (int a=0;a<6;a++){
            #pragma unroll
            for (int bb=a+1;bb<7;bb++){
                float acc=0.0f;
                #pragma unroll
                for (int i=0;i<7;i++) acc=fmaf(V[i*7+a],P2[i*7+bb],acc);
                To[OIDX(bb,a)]=acc;
            }
        }
        float zw[7];
        #pragma unroll
        for (int a=0;a<7;a++){
            float acc=ee[a]*Td[a]*w[a];
            #pragma unroll
            for (int bb=0;bb<7;bb++){
                if (bb==a) continue;
                float z=(bb<a)? (Ro[OIDX(a,bb)]*To[OIDX(a,bb)]) : (Ro[OIDX(bb,a)]*To[OIDX(bb,a)]);
                acc=fmaf(z,w[bb],acc);
            }
            zw[a]=acc;
        }
        #pragma unroll
        for (int i=0;i<7;i++){
            float acc=0.0f;
            #pragma unroll
            for (int a=0;a<7;a++) acc=fmaf(V[i*7+a],zw[a],acc);
            ws[OFF_RP + i*B_TOT + e] = tv[i]-acc;
        }
    }

    // Minv = V diag(1/ee) V^T
    #pragma unroll
    for (int i=0;i<7;i++){
        #pragma unroll
        for (int j=i;j<7;j++){
            float acc=0.0f;
            #pragma unroll
            for (int a=0;a<7;a++) acc=fmaf(V[i*7+a]*iee[a],V[j*7+a],acc);
            if (i==j) ws[OFF_MI + i*B_TOT + e]=acc;
            else      ws[OFF_MI + (NQ+OIDX(j,i))*B_TOT + e]=acc;
        }
    }
}

// ======== K4: M-net reverse (s), rhs, SPD solve -> out; 8 waves — unchanged ========
__global__ __launch_bounds__(512) void kd_solve(
    const float* __restrict__ WM0, const float* __restrict__ WM1, const float* __restrict__ WM2,
    const float* __restrict__ ws,
    float* __restrict__ out)
{
    __shared__ __align__(16) float w2t[H*MD];
    __shared__ float rr1fs[H*64];
    __shared__ float s0s[H*64];
    const int tid=threadIdx.x, lane=tid&63, wid=tid>>6;
    const int e = blockIdx.x*64+lane;

    for (int t=tid;t<MD*H;t+=512) w2t[(t&63)*MD+(t>>6)] = WM2[t];

    float sv[MD];
    #pragma unroll
    for (int m=0;m<MD;m++) sv[m]=ws[OFF_SV+m*B_TOT+e];
    __syncthreads();

    #pragma unroll
    for (int kk=0;kk<8;kk++){
        const int k=wid*8+kk;
        float wv[MD];
        #pragma unroll
        for (int c=0;c<7;c++) *(float4*)&wv[c*4] = *(const float4*)&w2t[k*MD + c*4];
        float acc=0.f;
        #pragma unroll
        for (int m=0;m<MD;m++) acc=fmaf(wv[m],sv[m],acc);
        float a1k=ws[OFF_A1+k*B_TOT+e];
        rr1fs[k*64+lane]=sigmoid_f(a1k)*acc;
        float a0k=ws[OFF_A0+k*B_TOT+e];
        s0s[k*64+lane]=sigmoid_f(a0k);
    }
    __syncthreads();

    float u[64];
    #pragma unroll
    for (int k=0;k<H;k++) u[k]=0.f;
    #pragma unroll
    for (int ii=0;ii<8;ii++){
        const int i=wid*8+ii;
        float r=rr1fs[i*64+lane];
        #pragma unroll
        for (int k=0;k<H;k++) u[k]=fmaf(WM1[i*H+k],r,u[k]);
    }

    float sp[NQ];
    #pragma unroll
    for (int d=0;d<NQ;d++) sp[d]=0.f;
    #pragma unroll
    for (int k=0;k<H;k++){
        float t2=s0s[k*64+lane]*u[k];
        #pragma unroll
        for (int d=0;d<NQ;d++) sp[d]=fmaf(WM0[k*NQ+d],t2,sp[d]);
    }
    __syncthreads();
    float* red = rr1fs;
    #pragma unroll
    for (int d=0;d<NQ;d++) red[(wid*NQ+d)*64+lane]=sp[d];
    __syncthreads();

    if (wid==0){
        #pragma unroll
        for (int w2=1;w2<8;w2++){
            #pragma unroll
            for (int d=0;d<NQ;d++) sp[d]+=red[(w2*NQ+d)*64+lane];
        }
        float rhs[NQ], mi[MD];
        #pragma unroll
        for (int d=0;d<NQ;d++)
            rhs[d] = ws[OFF_RP + d*B_TOT + e] + 0.5f*sp[d] - ws[OFF_G + d*B_TOT + e];
        #pragma unroll
        for (int t=0;t<MD;t++) mi[t]=ws[OFF_MI + t*B_TOT + e];
        #pragma unroll
        for (int i=0;i<NQ;i++){
            float acc=0.0f;
            #pragma unroll
            for (int jj=0;jj<NQ;jj++){
                int idx=(jj==i)? i : (NQ + ((jj>i)? OIDX(jj,i) : OIDX(i,jj)));
                acc=fmaf(mi[idx],rhs[jj],acc);
            }
            out[e*NQ+i]=acc;
        }
    }
}

extern "C" void kernel_launch(void* const* d_in, const int* in_sizes, int n_in,
                              void* d_out, int out_size, void* d_ws, size_t ws_size,
                              hipStream_t stream) {
    const float* q   = (const float*)d_in[0];
    const float* dq  = (const float*)d_in[1];
    const float* tau = (const float*)d_in[2];
    const float* WM0 = (const float*)d_in[3];
    const float* bM0 = (const float*)d_in[4];
    const float* WM1 = (const float*)d_in[5];
    const float* bM1 = (const float*)d_in[6];
    const float* WM2 = (const float*)d_in[7];
    const float* bM2 = (const float*)d_in[8];
    const float* WV0 = (const float*)d_in[9];
    const float* bV0 = (const float*)d_in[10];
    const float* WV1 = (const float*)d_in[11];
    const float* bV1 = (const float*)d_in[12];
    const float* WV2 = (const float*)d_in[13];
    float* ws  = (float*)d_ws;
    float* out = (float*)d_out;

    hipLaunchKernelGGL(k_mnet,   dim3(B_TOT/64), dim3(512), 0, stream,
                       q, dq, WM0, bM0, WM1, bM1, WM2, bM2, ws);
    hipLaunchKernelGGL(k_vnet,   dim3(B_TOT/64), dim3(512), 0, stream,
                       q, WV0, bV0, WV1, bV1, WV2, ws);
    hipLaunchKernelGGL(kb_eigen, dim3(B_TOT/64), dim3(64), 0, stream, dq, tau, ws);
    hipLaunchKernelGGL(kd_solve, dim3(B_TOT/64), dim3(512), 0, stream,
                       WM0, WM1, WM2, ws, out);
}